// Round 10
// baseline (434.305 us; speedup 1.0000x reference)
//
#include <hip/hip_runtime.h>

typedef _Float16 f16;
typedef __attribute__((ext_vector_type(8))) _Float16 f16x8;
typedef __attribute__((ext_vector_type(4))) float f32x4;

#define MFMA16(a, b, c) __builtin_amdgcn_mfma_f32_16x16x32_f16((a), (b), (c), 0, 0, 0)

__device__ __forceinline__ float silu_f(float x) {
    return x * __builtin_amdgcn_rcpf(1.f + __expf(-x));
}

__device__ __forceinline__ int pkf16(float a, float b) {
    typedef __attribute__((ext_vector_type(2))) __fp16 fp16x2;
    union { fp16x2 v; int i; } u;
    u.v = __builtin_amdgcn_cvt_pkrtz(a, b);
    return u.i;
}

__device__ __forceinline__ void pack4(f16* dst, float a, float b, float c, float d) {
    uint2 u; u.x = (unsigned)pkf16(a, b); u.y = (unsigned)pkf16(c, d);
    *(uint2*)dst = u;
}

__device__ __forceinline__ float upk(int u, int hi) {   // hi is compile-time
    union { __fp16 h[2]; int i; } x; x.i = u;
    return (float)x.h[hi];
}

// ---------------------------------------------------------------------------
// 256 blocks x 1024 threads (16 waves, 4/SIMD), 16 batch rows/block.
// Finer hidden split: L1/L2 1 nt-tile/wave; L3 on waves 0-7 (W3 from LDS);
// L4+RK redundant on all waves (validated r7 structure); kreg packed f16;
// 3 barriers/stage; b0 rebuilt via ds_bpermute.
// ---------------------------------------------------------------------------
__global__ __launch_bounds__(1024, 4) void ode_main(
        const float* __restrict__ y0, const float* __restrict__ tspan,
        const float* __restrict__ W1, const float* __restrict__ b1,
        const float* __restrict__ W2, const float* __restrict__ b2,
        const float* __restrict__ W3, const float* __restrict__ b3,
        const float* __restrict__ W4, const float* __restrict__ b4,
        float* __restrict__ out) {

    __shared__ f16 w3l[64 * 512];   // 64 frags: [f*512 + l*8 + j]  (64 KB)
    __shared__ f16 h1[16 * 264];
    __shared__ f16 h2[16 * 264];
    __shared__ f16 h3[16 * 136];
    __shared__ float bias[656];     // b1@0 b2@256 b3@512 b4@640, 652..655 = 0
    __shared__ float tsh[16];

    const int tid = threadIdx.x;
    const int l = tid & 63, w = tid >> 6;   // 16 waves
    const int g = l >> 4, col = l & 15;
    const int blk = blockIdx.x;
    const int bp0 = (32 * g + col) * 4;     // ds_bpermute byte addrs
    const int bp1 = bp0 + 64;

    // ---- persistent weight fragments (W3 goes to LDS instead) ----
    f16x8 w1f, w2f[8], w4f[4];
    {
        const int n = w * 16 + col;
#pragma unroll
        for (int j = 0; j < 8; ++j) {
            const int k = g * 8 + j;
            w1f[j] = (k < 13) ? (f16)W1[k * 256 + n] : (f16)0.f;
        }
#pragma unroll
        for (int kt = 0; kt < 8; ++kt)
#pragma unroll
            for (int j = 0; j < 8; ++j)
                w2f[kt][j] = (f16)W2[(kt * 32 + g * 8 + j) * 256 + n];
    }
#pragma unroll
    for (int kt = 0; kt < 4; ++kt)
#pragma unroll
        for (int j = 0; j < 8; ++j)
            w4f[kt][j] = (col < 12) ? (f16)W4[(kt * 32 + g * 8 + j) * 12 + col] : (f16)0.f;

    // ---- stage W3 into LDS (frag layout; each wave stages 4 frags) ----
#pragma unroll
    for (int q = 0; q < 4; ++q) {
        const int f = w * 4 + q, nt = f >> 3, kt = f & 7;
        f16x8 tv;
#pragma unroll
        for (int j = 0; j < 8; ++j)
            tv[j] = (f16)W3[(kt * 32 + g * 8 + j) * 128 + nt * 16 + col];
        *(f16x8*)&w3l[f * 512 + l * 8] = tv;
    }

    // ---- LDS init ----
    for (int i = tid; i < 656; i += 1024) {
        float v = 0.f;
        if (i < 256) v = b1[i];
        else if (i < 512) v = b2[i - 256];
        else if (i < 640) v = b3[i - 512];
        else if (i < 652) v = b4[i - 640];
        bias[i] = v;
    }
    if (tid < 16) tsh[tid] = tspan[tid];

    // ---- initial RK state (comp c=4g+j of batch col, identical on all waves) ----
    float yreg[4];
#pragma unroll
    for (int j = 0; j < 4; ++j) {
        const int c = 4 * g + j;
        yreg[j] = (c < 13) ? y0[(blk * 16 + col) * 13 + c] : 0.f;
    }
    if (w == 0) {
#pragma unroll
        for (int j = 0; j < 4; ++j) {
            const int c = 4 * g + j;
            if (c < 13) out[(size_t)(blk * 16 + col) * 13 + c] = yreg[j];
        }
    }
    __syncthreads();   // bias/tsh/w3l ready

    static constexpr float AT[5][5] = {
        {0.2f, 0.f, 0.f, 0.f, 0.f},
        {3.f/40.f, 9.f/40.f, 0.f, 0.f, 0.f},
        {44.f/45.f, -56.f/15.f, 32.f/9.f, 0.f, 0.f},
        {19372.f/6561.f, -25360.f/2187.f, 64448.f/6561.f, -212.f/729.f, 0.f},
        {9017.f/3168.f, -355.f/33.f, 46732.f/5247.f, 49.f/176.f, -5103.f/18656.f}
    };

    int kpk[6][2];   // k-stages packed f16 pairs: [s][0]=(k0,k1), [s][1]=(k2,k3)
    f16x8 b0;
    {
        int h01 = pkf16(yreg[0], yreg[1]), h23 = pkf16(yreg[2], yreg[3]);
        int u0 = __builtin_amdgcn_ds_bpermute(bp0, h01);
        int u1 = __builtin_amdgcn_ds_bpermute(bp0, h23);
        int u2 = __builtin_amdgcn_ds_bpermute(bp1, h01);
        int u3 = __builtin_amdgcn_ds_bpermute(bp1, h23);
        if (g >= 2) { u0 = 0; u1 = 0; u2 = 0; u3 = 0; }
        union { int i[4]; f16x8 v; } u; u.i[0]=u0; u.i[1]=u1; u.i[2]=u2; u.i[3]=u3;
        b0 = u.v;
    }

    for (int step = 0; step < 30; ++step) {
        const float hstep = (tsh[(step >> 1) + 1] - tsh[step >> 1]) * 0.5f;
#pragma unroll
        for (int s = 0; s < 6; ++s) {
            // ---- phase A: L1, 1 nt-tile per wave ----
            {
                f32x4 acc = MFMA16(w1f, b0, ((f32x4){0.f,0.f,0.f,0.f}));
                float4 bb = *(const float4*)&bias[w * 16 + g * 4];
                pack4(&h1[col * 264 + w * 16 + g * 4],
                      silu_f(acc[0] + bb.x), silu_f(acc[1] + bb.y),
                      silu_f(acc[2] + bb.z), silu_f(acc[3] + bb.w));
            }
            __syncthreads();
            // ---- phase B: L2, 1 nt-tile per wave, 2 half-K chains ----
            {
                f32x4 aL = (f32x4){0.f,0.f,0.f,0.f}, aH = aL;
#pragma unroll
                for (int kt = 0; kt < 4; ++kt) {
                    f16x8 hL = *(const f16x8*)&h1[col * 264 + kt * 32 + g * 8];
                    f16x8 hH = *(const f16x8*)&h1[col * 264 + (kt + 4) * 32 + g * 8];
                    aL = MFMA16(w2f[kt], hL, aL);
                    aH = MFMA16(w2f[kt + 4], hH, aH);
                }
                f32x4 acc = aL + aH;
                float4 bb = *(const float4*)&bias[256 + w * 16 + g * 4];
                pack4(&h2[col * 264 + w * 16 + g * 4],
                      silu_f(acc[0] + bb.x), silu_f(acc[1] + bb.y),
                      silu_f(acc[2] + bb.z), silu_f(acc[3] + bb.w));
            }
            __syncthreads();
            // ---- phase C: L3 on waves 0-7, W3 frags from LDS ----
            if (w < 8) {
                f32x4 aL = (f32x4){0.f,0.f,0.f,0.f}, aH = aL;
#pragma unroll
                for (int kt = 0; kt < 4; ++kt) {
                    f16x8 wL = *(const f16x8*)&w3l[(w * 8 + kt) * 512 + l * 8];
                    f16x8 hL = *(const f16x8*)&h2[col * 264 + kt * 32 + g * 8];
                    aL = MFMA16(wL, hL, aL);
                    f16x8 wH = *(const f16x8*)&w3l[(w * 8 + kt + 4) * 512 + l * 8];
                    f16x8 hH = *(const f16x8*)&h2[col * 264 + (kt + 4) * 32 + g * 8];
                    aH = MFMA16(wH, hH, aH);
                }
                f32x4 acc = aL + aH;
                float4 bb = *(const float4*)&bias[512 + w * 16 + g * 4];
                pack4(&h3[col * 136 + w * 16 + g * 4],
                      silu_f(acc[0] + bb.x), silu_f(acc[1] + bb.y),
                      silu_f(acc[2] + bb.z), silu_f(acc[3] + bb.w));
            }
            __syncthreads();
            // ---- phase D: L4 + RK, redundant on all waves (no barrier after) ----
            float x[4];
            {
                f32x4 aL = (f32x4){0.f,0.f,0.f,0.f}, aH = aL;
#pragma unroll
                for (int kt = 0; kt < 2; ++kt) {
                    f16x8 hL = *(const f16x8*)&h3[col * 136 + kt * 32 + g * 8];
                    aL = MFMA16(w4f[kt], hL, aL);
                    f16x8 hH = *(const f16x8*)&h3[col * 136 + (kt + 2) * 32 + g * 8];
                    aH = MFMA16(w4f[kt + 2], hH, aH);
                }
                f32x4 a4 = aL + aH;
                float4 bb4 = *(const float4*)&bias[640 + g * 4];   // zeros for comps >= 12
                float kc[4] = {a4[0] + bb4.x, a4[1] + bb4.y, a4[2] + bb4.z, a4[3] + bb4.w};
                kpk[s][0] = pkf16(kc[0], kc[1]);
                kpk[s][1] = pkf16(kc[2], kc[3]);
                if (s < 5) {
#pragma unroll
                    for (int j = 0; j < 4; ++j) {
                        float a2 = AT[s][s] * kc[j];
#pragma unroll
                        for (int i = 0; i < 5; ++i)
                            if (i < s) a2 += AT[s][i] * upk(kpk[i][j >> 1], j & 1);
                        x[j] = yreg[j] + hstep * a2;
                    }
                } else {
#pragma unroll
                    for (int j = 0; j < 4; ++j) {
                        float a2 = (35.f/384.f)   * upk(kpk[0][j >> 1], j & 1)
                                 + (500.f/1113.f) * upk(kpk[2][j >> 1], j & 1)
                                 + (125.f/192.f)  * upk(kpk[3][j >> 1], j & 1)
                                 + (-2187.f/6784.f) * upk(kpk[4][j >> 1], j & 1)
                                 + (11.f/84.f)    * kc[j];
                        yreg[j] += hstep * a2;
                        x[j] = yreg[j];
                    }
                    if ((step & 1) && w == 0) {
                        const int slot = (step + 1) >> 1;
#pragma unroll
                        for (int j = 0; j < 4; ++j) {
                            const int c = 4 * g + j;
                            if (c < 13)
                                out[((size_t)slot * 4096 + blk * 16 + col) * 13 + c] = yreg[j];
                        }
                    }
                }
            }
            // ---- rebuild b0 for next stage (in-register transpose) ----
            {
                int h01 = pkf16(x[0], x[1]), h23 = pkf16(x[2], x[3]);
                int u0 = __builtin_amdgcn_ds_bpermute(bp0, h01);
                int u1 = __builtin_amdgcn_ds_bpermute(bp0, h23);
                int u2 = __builtin_amdgcn_ds_bpermute(bp1, h01);
                int u3 = __builtin_amdgcn_ds_bpermute(bp1, h23);
                if (g >= 2) { u0 = 0; u1 = 0; u2 = 0; u3 = 0; }
                union { int i[4]; f16x8 v; } u; u.i[0]=u0; u.i[1]=u1; u.i[2]=u2; u.i[3]=u3;
                b0 = u.v;
            }
        }
    }
}

extern "C" void kernel_launch(void* const* d_in, const int* in_sizes, int n_in,
                              void* d_out, int out_size, void* d_ws, size_t ws_size,
                              hipStream_t stream) {
    (void)in_sizes; (void)n_in; (void)out_size; (void)d_ws; (void)ws_size;
    const float* y0 = (const float*)d_in[0];
    const float* ts = (const float*)d_in[1];
    const float* W1 = (const float*)d_in[2];
    const float* b1 = (const float*)d_in[3];
    const float* W2 = (const float*)d_in[4];
    const float* b2 = (const float*)d_in[5];
    const float* W3 = (const float*)d_in[6];
    const float* b3 = (const float*)d_in[7];
    const float* W4 = (const float*)d_in[8];
    const float* b4 = (const float*)d_in[9];
    float* out = (float*)d_out;

    hipLaunchKernelGGL(ode_main, dim3(256), dim3(1024), 0, stream,
                       y0, ts, W1, b1, W2, b2, W3, b3, W4, b4, out);
}

// Round 11
// 356.037 us; speedup vs baseline: 1.2198x; 1.2198x over previous
//
#include <hip/hip_runtime.h>

typedef _Float16 f16;
typedef __attribute__((ext_vector_type(8))) _Float16 f16x8;
typedef __attribute__((ext_vector_type(4))) float f32x4;

#define MFMA16(a, b, c) __builtin_amdgcn_mfma_f32_16x16x32_f16((a), (b), (c), 0, 0, 0)

__device__ __forceinline__ float silu_f(float x) {
    // x * sigmoid(x), exp via bare v_exp_f32 (2^t), rcp via v_rcp_f32
    return x * __builtin_amdgcn_rcpf(1.f + __builtin_amdgcn_exp2f(x * -1.44269504088896f));
}

__device__ __forceinline__ int pkf16(float a, float b) {
    typedef __attribute__((ext_vector_type(2))) __fp16 fp16x2;
    union { fp16x2 v; int i; } u;
    u.v = __builtin_amdgcn_cvt_pkrtz(a, b);   // __fp16x2 on gfx950
    return u.i;
}

__device__ __forceinline__ void pack4(f16* dst, float a, float b, float c, float d) {
    uint2 u; u.x = (unsigned)pkf16(a, b); u.y = (unsigned)pkf16(c, d);
    *(uint2*)dst = u;
}

// ---------------------------------------------------------------------------
// 256 blocks x 512 threads (8 waves), 16 batch rows/block.  [r7 champion base]
// 3 barriers/stage; L4+RK redundant on all waves; b0 via ds_bpermute.
// r11: bias hoisted to registers (no per-stage LDS bias reads); exp2 silu.
//   D-frag lane (g,col): rows 4g+r (comp), col=batch  ->  RK state yreg/kreg
//   L1 B-frag lane (g,col): k=8g+j of batch col  <- lanes 16*(2g)+col, 16*(2g+1)+col
// ---------------------------------------------------------------------------
__global__ __launch_bounds__(512, 2) void ode_main(
        const float* __restrict__ y0, const float* __restrict__ tspan,
        const float* __restrict__ W1, const float* __restrict__ b1,
        const float* __restrict__ W2, const float* __restrict__ b2,
        const float* __restrict__ W3, const float* __restrict__ b3,
        const float* __restrict__ W4, const float* __restrict__ b4,
        float* __restrict__ out) {

    __shared__ f16 h1[16 * 264];
    __shared__ f16 h2[16 * 264];
    __shared__ f16 h3[16 * 136];
    __shared__ float tsh[16];

    const int tid = threadIdx.x;
    const int l = tid & 63, w = tid >> 6;
    const int g = l >> 4, col = l & 15;
    const int blk = blockIdx.x;
    const int bp0 = (32 * g + col) * 4;    // byte addr of lane 16*(2g)+col
    const int bp1 = bp0 + 64;              // lane 16*(2g+1)+col

    // ---- persistent weight fragments ----
    f16x8 w1f[2], w2f[2][8], w3f[8], w4f[4];
#pragma unroll
    for (int a = 0; a < 2; ++a) {
        const int n = (2 * w + a) * 16 + col;
#pragma unroll
        for (int j = 0; j < 8; ++j) {
            const int k = g * 8 + j;
            w1f[a][j] = (k < 13) ? (f16)W1[k * 256 + n] : (f16)0.f;
        }
#pragma unroll
        for (int kt = 0; kt < 8; ++kt)
#pragma unroll
            for (int j = 0; j < 8; ++j)
                w2f[a][kt][j] = (f16)W2[(kt * 32 + g * 8 + j) * 256 + n];
    }
    {
        const int n3 = w * 16 + col;
#pragma unroll
        for (int kt = 0; kt < 8; ++kt)
#pragma unroll
            for (int j = 0; j < 8; ++j)
                w3f[kt][j] = (f16)W3[(kt * 32 + g * 8 + j) * 128 + n3];
    }
#pragma unroll
    for (int kt = 0; kt < 4; ++kt)
#pragma unroll
        for (int j = 0; j < 8; ++j)
            w4f[kt][j] = (col < 12) ? (f16)W4[(kt * 32 + g * 8 + j) * 12 + col] : (f16)0.f;

    // ---- bias hoisted to registers (loop-invariant) ----
    float4 bb1[2], bb2[2], bb3, bb4;
#pragma unroll
    for (int a = 0; a < 2; ++a) {
        const int nt = 2 * w + a;
        bb1[a] = *(const float4*)&b1[nt * 16 + g * 4];
        bb2[a] = *(const float4*)&b2[nt * 16 + g * 4];
    }
    bb3 = *(const float4*)&b3[w * 16 + g * 4];
    bb4 = (g < 3) ? *(const float4*)&b4[g * 4] : make_float4(0.f, 0.f, 0.f, 0.f);

    if (tid < 16) tsh[tid] = tspan[tid];

    // ---- initial RK state in registers (comp c=4g+j of batch col) ----
    float yreg[4];
#pragma unroll
    for (int j = 0; j < 4; ++j) {
        const int c = 4 * g + j;
        yreg[j] = (c < 13) ? y0[(blk * 16 + col) * 13 + c] : 0.f;
    }
    if (w == 0) {
#pragma unroll
        for (int j = 0; j < 4; ++j) {
            const int c = 4 * g + j;
            if (c < 13) out[(size_t)(blk * 16 + col) * 13 + c] = yreg[j];
        }
    }
    __syncthreads();   // tsh ready

    static constexpr float AT[5][5] = {
        {0.2f, 0.f, 0.f, 0.f, 0.f},
        {3.f/40.f, 9.f/40.f, 0.f, 0.f, 0.f},
        {44.f/45.f, -56.f/15.f, 32.f/9.f, 0.f, 0.f},
        {19372.f/6561.f, -25360.f/2187.f, 64448.f/6561.f, -212.f/729.f, 0.f},
        {9017.f/3168.f, -355.f/33.f, 46732.f/5247.f, 49.f/176.f, -5103.f/18656.f}
    };

    float kreg[6][4];
    f16x8 b0;
    {   // b0 from initial y
        int h01 = pkf16(yreg[0], yreg[1]), h23 = pkf16(yreg[2], yreg[3]);
        int u0 = __builtin_amdgcn_ds_bpermute(bp0, h01);
        int u1 = __builtin_amdgcn_ds_bpermute(bp0, h23);
        int u2 = __builtin_amdgcn_ds_bpermute(bp1, h01);
        int u3 = __builtin_amdgcn_ds_bpermute(bp1, h23);
        if (g >= 2) { u0 = 0; u1 = 0; u2 = 0; u3 = 0; }
        union { int i[4]; f16x8 v; } u; u.i[0]=u0; u.i[1]=u1; u.i[2]=u2; u.i[3]=u3;
        b0 = u.v;
    }

    for (int step = 0; step < 30; ++step) {
        const float hstep = (tsh[(step >> 1) + 1] - tsh[step >> 1]) * 0.5f;
#pragma unroll
        for (int s = 0; s < 6; ++s) {
            // ---- phase A: L1 (b0 in registers) -> h1 ----
            f32x4 acc[2];
#pragma unroll
            for (int a = 0; a < 2; ++a) acc[a] = (f32x4){0.f, 0.f, 0.f, 0.f};
#pragma unroll
            for (int a = 0; a < 2; ++a) acc[a] = MFMA16(w1f[a], b0, acc[a]);
#pragma unroll
            for (int a = 0; a < 2; ++a) {
                const int nt = 2 * w + a;
                pack4(&h1[col * 264 + nt * 16 + g * 4],
                      silu_f(acc[a][0] + bb1[a].x), silu_f(acc[a][1] + bb1[a].y),
                      silu_f(acc[a][2] + bb1[a].z), silu_f(acc[a][3] + bb1[a].w));
            }
            __syncthreads();
            // ---- phase B: L2 ----
            f16x8 hf[8];
#pragma unroll
            for (int kt = 0; kt < 8; ++kt) hf[kt] = *(const f16x8*)&h1[col * 264 + kt * 32 + g * 8];
#pragma unroll
            for (int a = 0; a < 2; ++a) acc[a] = (f32x4){0.f, 0.f, 0.f, 0.f};
#pragma unroll
            for (int kt = 0; kt < 8; ++kt)
#pragma unroll
                for (int a = 0; a < 2; ++a) acc[a] = MFMA16(w2f[a][kt], hf[kt], acc[a]);
#pragma unroll
            for (int a = 0; a < 2; ++a) {
                const int nt = 2 * w + a;
                pack4(&h2[col * 264 + nt * 16 + g * 4],
                      silu_f(acc[a][0] + bb2[a].x), silu_f(acc[a][1] + bb2[a].y),
                      silu_f(acc[a][2] + bb2[a].z), silu_f(acc[a][3] + bb2[a].w));
            }
            __syncthreads();
            // ---- phase C: L3 ----
#pragma unroll
            for (int kt = 0; kt < 8; ++kt) hf[kt] = *(const f16x8*)&h2[col * 264 + kt * 32 + g * 8];
            f32x4 a3 = (f32x4){0.f, 0.f, 0.f, 0.f};
#pragma unroll
            for (int kt = 0; kt < 8; ++kt) a3 = MFMA16(w3f[kt], hf[kt], a3);
            pack4(&h3[col * 136 + w * 16 + g * 4],
                  silu_f(a3[0] + bb3.x), silu_f(a3[1] + bb3.y),
                  silu_f(a3[2] + bb3.z), silu_f(a3[3] + bb3.w));
            __syncthreads();
            // ---- phase D: L4 + RK, redundant on ALL waves; no barrier after ----
            f16x8 h3f[4];
#pragma unroll
            for (int kt = 0; kt < 4; ++kt) h3f[kt] = *(const f16x8*)&h3[col * 136 + kt * 32 + g * 8];
            f32x4 a4 = (f32x4){0.f, 0.f, 0.f, 0.f};
#pragma unroll
            for (int kt = 0; kt < 4; ++kt) a4 = MFMA16(w4f[kt], h3f[kt], a4);
            kreg[s][0] = a4[0] + bb4.x; kreg[s][1] = a4[1] + bb4.y;
            kreg[s][2] = a4[2] + bb4.z; kreg[s][3] = a4[3] + bb4.w;
            float x[4];
            if (s < 5) {
#pragma unroll
                for (int j = 0; j < 4; ++j) {
                    float a2 = 0.f;
#pragma unroll
                    for (int i = 0; i <= s; ++i) a2 += AT[s][i] * kreg[i][j];
                    x[j] = yreg[j] + hstep * a2;
                }
            } else {
#pragma unroll
                for (int j = 0; j < 4; ++j) {
                    float a2 = (35.f/384.f) * kreg[0][j] + (500.f/1113.f) * kreg[2][j]
                             + (125.f/192.f) * kreg[3][j] + (-2187.f/6784.f) * kreg[4][j]
                             + (11.f/84.f) * kreg[5][j];
                    yreg[j] += hstep * a2;
                    x[j] = yreg[j];
                }
                if ((step & 1) && w == 0) {
                    const int slot = (step + 1) >> 1;
#pragma unroll
                    for (int j = 0; j < 4; ++j) {
                        const int c = 4 * g + j;
                        if (c < 13)
                            out[((size_t)slot * 4096 + blk * 16 + col) * 13 + c] = yreg[j];
                    }
                }
            }
            // ---- rebuild b0 for next stage (in-register transpose) ----
            {
                int h01 = pkf16(x[0], x[1]), h23 = pkf16(x[2], x[3]);
                int u0 = __builtin_amdgcn_ds_bpermute(bp0, h01);
                int u1 = __builtin_amdgcn_ds_bpermute(bp0, h23);
                int u2 = __builtin_amdgcn_ds_bpermute(bp1, h01);
                int u3 = __builtin_amdgcn_ds_bpermute(bp1, h23);
                if (g >= 2) { u0 = 0; u1 = 0; u2 = 0; u3 = 0; }
                union { int i[4]; f16x8 v; } u; u.i[0]=u0; u.i[1]=u1; u.i[2]=u2; u.i[3]=u3;
                b0 = u.v;
            }
        }
    }
}

extern "C" void kernel_launch(void* const* d_in, const int* in_sizes, int n_in,
                              void* d_out, int out_size, void* d_ws, size_t ws_size,
                              hipStream_t stream) {
    (void)in_sizes; (void)n_in; (void)out_size; (void)d_ws; (void)ws_size;
    const float* y0 = (const float*)d_in[0];
    const float* ts = (const float*)d_in[1];
    const float* W1 = (const float*)d_in[2];
    const float* b1 = (const float*)d_in[3];
    const float* W2 = (const float*)d_in[4];
    const float* b2 = (const float*)d_in[5];
    const float* W3 = (const float*)d_in[6];
    const float* b3 = (const float*)d_in[7];
    const float* W4 = (const float*)d_in[8];
    const float* b4 = (const float*)d_in[9];
    float* out = (float*)d_out;

    hipLaunchKernelGGL(ode_main, dim3(256), dim3(512), 0, stream,
                       y0, ts, W1, b1, W2, b2, W3, b3, W4, b4, out);
}